// Round 7
// baseline (363.579 us; speedup 1.0000x reference)
//
#include <hip/hip_runtime.h>
#include <hip/hip_bf16.h>
#include <cstdint>
#include <cstddef>

typedef __bf16 bf16_t;
typedef bf16_t bf16x8 __attribute__((ext_vector_type(8)));
typedef float f32x4 __attribute__((ext_vector_type(4)));

#define BN_EPS 1e-5f

// r7: per-lane GLOBAL addrs for global_load_lds stay lane-order contiguous;
// LDS swizzles only via pre-swizzled SOURCE addrs.
// r11 (REGRESSED): duplicated reg-direct B reads = 2x traffic.
// r12/r13: inner-loop schedule variants flat (~291-302) at 8 waves/CU.
// r14 (WIN 291->174): per-block fusion, 12 waves/CU. h1 HBM round-trip left.
// r15: h1 LDS-only killed 210MB traffic (322->112MB) but dur 174->220:
// latency-bound at 8 waves/CU (MfmaUtil 19%, HBM 6%, VALU 12%).
// r16 (bench infra failed — resubmitted as r17 with rule-#18 fences):
// same dataflow, 8-wave blocks + <=128 VGPR -> 16 waves/CU (4/SIMD).
// acc2[4][4]=64 regs (wave owns 64 N-cols), gemm1 16-col sub-passes
// (acc1=16 regs), depth-2 ping-pong B1 staging with counted vmcnt(1).
// sched_barrier(0) after every inline-asm wait: hipcc may hoist register-only
// MFMA past an asm lgkmcnt despite the "memory" clobber (learn_hip r263/r282).
__device__ __forceinline__ void async_load16(const bf16_t* g, bf16_t* lds) {
  __builtin_amdgcn_global_load_lds(
      (__attribute__((address_space(1))) uint32_t*)(g),
      (__attribute__((address_space(3))) uint32_t*)(lds),
      16, 0, 0);
}

// ---- Weight prep (transposes + BN folds), tiny ------------------------------
__global__ void prep_weights_kernel(const float* __restrict__ W1, const float* __restrict__ W2,
                                    const float* b1, const float* g1, const float* be1,
                                    const float* m1, const float* v1,
                                    const float* b2, const float* g2, const float* be2,
                                    const float* m2, const float* v2,
                                    bf16_t* __restrict__ W1T, bf16_t* __restrict__ W2T,
                                    float* s1, float* t1, float* s2, float* t2,
                                    float* w1last) {
  const int b = blockIdx.x;
  if (b < 192) {
    const float* src;
    bf16_t* dst;
    int R, C, bx, by;
    if (b < 64) { src = W1; dst = W1T; R = 256; C = 1024; bx = b & 15; by = b >> 4; }
    else        { src = W2; dst = W2T; R = 1024; C = 512; bx = (b - 64) & 7; by = (b - 64) >> 3; }
    __shared__ bf16_t tile[64][66];
    const int r0 = by * 64, c0 = bx * 64;
    const int tc = threadIdx.x & 63;
    const int tr4 = threadIdx.x >> 6;
#pragma unroll
    for (int i = 0; i < 16; ++i) {
      int r = i * 4 + tr4;
      tile[r][tc] = (bf16_t)src[(size_t)(r0 + r) * C + c0 + tc];  // coalesced read
    }
    __syncthreads();
#pragma unroll
    for (int i = 0; i < 16; ++i) {
      int rr = i * 4 + tr4;
      dst[(size_t)(c0 + rr) * R + r0 + tc] = tile[tc][rr];  // coalesced write
    }
  } else {
    for (int i = threadIdx.x; i < 1024; i += 256) {
      float s = g1[i] * rsqrtf(v1[i] + BN_EPS);
      s1[i] = s;
      t1[i] = be1[i] - m1[i] * s + b1[i] * s;  // bn(z+b1) = z*s + t
      w1last[i] = W1[256 * 1024 + i];          // conv-feature row (coalesced)
      if (i < 512) {
        float s2v = g2[i] * rsqrtf(v2[i] + BN_EPS);
        s2[i] = s2v;
        t2[i] = be2[i] - m2[i] * s2v + b2[i] * s2v;
      }
    }
  }
}

// ---- Fully-fused per-block MLP: 64 rows, 8 waves, h1 LDS-only ---------------
// LDS 80 KB: As[64][256] bf16 32K (chunk-swizzled) | h1c[64][256] bf16 32K
// (chunk-swizzled; convs[64] overlays pre-use) | B1s 8 waves x 2 stages x 1K
// (16K; outW[8][64] overlays at the end).
__global__ __launch_bounds__(512, 4) void fused_mlp(
    const float* __restrict__ x,
    const bf16_t* __restrict__ W1T, const bf16_t* __restrict__ W2T,
    const float* __restrict__ s1, const float* __restrict__ t1,
    const float* __restrict__ w1last,
    const float* __restrict__ s2, const float* __restrict__ t2,
    const float* __restrict__ W3, const float* __restrict__ b3,
    float* __restrict__ out) {
  __shared__ __align__(16) unsigned char smem[81920];
  const int tid = threadIdx.x;
  const int lane = tid & 63;
  const int w = tid >> 6;          // 0..7
  const int l15 = lane & 15;
  const int quad = lane >> 4;
  const int mTile = blockIdx.x * 64;

  bf16_t* As = (bf16_t*)smem;                 // [64][256], chunk-swizzled
  bf16_t* h1c = (bf16_t*)(smem + 32768);      // [64][256], chunk-swizzled
  float* convs = (float*)(smem + 32768);      // overlay (pre-h1c use)
  bf16_t* B1s = (bf16_t*)(smem + 65536);      // [8 waves][2 bufs][512 elems]
  float* outW = (float*)(smem + 65536);       // overlay (post-B1s use)

  // ---- prologue: x fp32 -> bf16 into As (swizzled), per-row conv ----------
  {
    const int rsub = lane >> 5;     // 0..1
    const int cc = lane & 31;       // 8-elem chunk within row
#pragma unroll
    for (int i = 0; i < 4; ++i) {
      int row = w * 8 + i * 2 + rsub;
      const float* gx = x + (size_t)(mTile + row) * 256 + cc * 8;
      const float4 a = *(const float4*)gx;
      const float4 bq = *(const float4*)(gx + 4);
      float s = a.x + a.y + a.z + a.w + bq.x + bq.y + bq.z + bq.w;
      bf16x8 v = {(bf16_t)a.x, (bf16_t)a.y, (bf16_t)a.z, (bf16_t)a.w,
                  (bf16_t)bq.x, (bf16_t)bq.y, (bf16_t)bq.z, (bf16_t)bq.w};
      *(bf16x8*)(As + row * 256 + (cc ^ (row & 7)) * 8) = v;
#pragma unroll
      for (int m = 1; m <= 16; m <<= 1) s += __shfl_xor(s, m);  // 32-lane groups
      if (cc == 0) convs[row] = (s > 0.0f) ? 1.0f : 0.0f;  // mean>0 <=> sum>0
    }
  }
  __syncthreads();  // As + convs visible

  // Conv feature bitmask over the 16 output rows this lane owns.
  unsigned cmask = 0;
#pragma unroll
  for (int ti = 0; ti < 4; ++ti)
#pragma unroll
    for (int r = 0; r < 4; ++r)
      if (convs[ti * 16 + quad * 4 + r] > 0.5f) cmask |= (1u << (ti * 4 + r));
  __syncthreads();  // all convs reads done before h1c overlay is written

  bf16_t* B1w = B1s + w * 1024;         // wave-private: 2 bufs x 512 elems
  const int srow = lane >> 2;           // 0..15
  const int schunk = (lane & 3) ^ ((lane >> 3) & 3);   // pre-swizzled src chunk
  const int rchunk = quad ^ ((l15 >> 1) & 3);          // read-side inverse

  // Persistent gemm2 accumulators: wave owns N-cols [w*64, w*64+64).
  f32x4 acc2[4][4];
#pragma unroll
  for (int i = 0; i < 4; ++i)
#pragma unroll
    for (int j = 0; j < 4; ++j) {
      f32x4 z = {0.f, 0.f, 0.f, 0.f};
      acc2[i][j] = z;
    }

  for (int c = 0; c < 4; ++c) {
    // ---- gemm1: wave w owns cols c*256 + w*32 .. +31, two 16-col sub-passes.
#pragma unroll
    for (int sp = 0; sp < 2; ++sp) {
      const int colbase = c * 256 + w * 32 + sp * 16;
      f32x4 acc1[4];
#pragma unroll
      for (int i = 0; i < 4; ++i) {
        f32x4 z = {0.f, 0.f, 0.f, 0.f};
        acc1[i] = z;
      }

      const bf16_t* gB1 = W1T + (size_t)(colbase + srow) * 256 + schunk * 8;

      // Depth-2 ping-pong prologue: ks=0 -> buf0, ks=1 -> buf1 (1 load each).
      async_load16(gB1, B1w + lane * 8);
      async_load16(gB1 + 32, B1w + 512 + lane * 8);

      for (int ks = 0; ks < 8; ++ks) {
        if (ks < 7)
          asm volatile("s_waitcnt vmcnt(1)" ::: "memory");  // stage ks landed
        else
          asm volatile("s_waitcnt vmcnt(0)" ::: "memory");
        __builtin_amdgcn_sched_barrier(0);  // rule #18: pin reads below wait

        bf16x8 bfr = *(const bf16x8*)(B1w + (ks & 1) * 512 + l15 * 32 + rchunk * 8);
        bf16x8 af[4];
#pragma unroll
        for (int ti = 0; ti < 4; ++ti)
          af[ti] = *(const bf16x8*)(As + (ti * 16 + l15) * 256 +
                                    ((ks * 4 + quad) ^ (l15 & 7)) * 8);

        asm volatile("s_waitcnt lgkmcnt(0)" ::: "memory");  // frags in regs
        __builtin_amdgcn_sched_barrier(0);  // rule #18: MFMA must not hoist
        if (ks < 6)
          async_load16(gB1 + (ks + 2) * 32, B1w + (ks & 1) * 512 + lane * 8);

        __builtin_amdgcn_s_setprio(1);
#pragma unroll
        for (int ti = 0; ti < 4; ++ti)
          acc1[ti] = __builtin_amdgcn_mfma_f32_16x16x32_bf16(af[ti], bfr, acc1[ti], 0, 0, 0);
        __builtin_amdgcn_s_setprio(0);
      }

      if (sp == 0) __syncthreads();  // WAR: all waves done reading h1c (chunk c-1)

      // Epilogue: conv rank-1 + BN1 + ReLU -> h1c (LDS, swizzled)
      const int ccol = colbase + l15;
      const float sc1 = s1[ccol];
      const float tc1 = t1[ccol];
      const float wl1 = w1last[ccol];
      const int colc = w * 32 + sp * 16 + l15;   // 0..255 within chunk
#pragma unroll
      for (int ti = 0; ti < 4; ++ti)
#pragma unroll
        for (int r = 0; r < 4; ++r) {
          const int rowl = ti * 16 + quad * 4 + r;
          const float cfv = ((cmask >> (ti * 4 + r)) & 1u) ? 1.0f : 0.0f;
          float z = acc1[ti][r] + cfv * wl1;
          z = fmaxf(z * sc1 + tc1, 0.f);
          const int c8 = (colc >> 3) ^ (rowl & 7);
          h1c[rowl * 256 + c8 * 8 + (l15 & 7)] = (bf16_t)z;
        }
    }
    __syncthreads();  // h1c chunk complete + visible

    // ---- gemm2 partial: K-range [c*256,(c+1)*256), N = wave's 64 cols.
    // B fragments reg-direct from L2 (disjoint per wave); A from h1c LDS.
    // Zero barriers: compiler pipelines the 8 steps freely.
    const bf16_t* gB2 = W2T + (size_t)(w * 64 + l15) * 1024 + c * 256 + quad * 8;
#pragma unroll
    for (int s = 0; s < 8; ++s) {
      bf16x8 af2[4], bfr2[4];
#pragma unroll
      for (int tj = 0; tj < 4; ++tj)
        bfr2[tj] = *(const bf16x8*)(gB2 + (size_t)(tj * 16) * 1024 + s * 32);
#pragma unroll
      for (int ti = 0; ti < 4; ++ti)
        af2[ti] = *(const bf16x8*)(h1c + (ti * 16 + l15) * 256 +
                                   ((s * 4 + quad) ^ (l15 & 7)) * 8);
      __builtin_amdgcn_s_setprio(1);
#pragma unroll
      for (int ti = 0; ti < 4; ++ti)
#pragma unroll
        for (int tj = 0; tj < 4; ++tj)
          acc2[ti][tj] = __builtin_amdgcn_mfma_f32_16x16x32_bf16(af2[ti], bfr2[tj], acc2[ti][tj], 0, 0, 0);
      __builtin_amdgcn_s_setprio(0);
    }
  }

  // ---- final epilogue: BN2 + ReLU + dot W3 over this wave's 64 N-cols ----
  float sc[4], tcs[4], w3c[4];
#pragma unroll
  for (int tj = 0; tj < 4; ++tj) {
    int ccol = w * 64 + tj * 16 + l15;
    sc[tj] = s2[ccol];
    tcs[tj] = t2[ccol];
    w3c[tj] = W3[ccol];
  }
  float rowpv[4][4];
#pragma unroll
  for (int ti = 0; ti < 4; ++ti)
#pragma unroll
    for (int r = 0; r < 4; ++r) {
      float pv = 0.f;
#pragma unroll
      for (int tj = 0; tj < 4; ++tj) {
        float z = fmaxf(acc2[ti][tj][r] * sc[tj] + tcs[tj], 0.f);
        pv += z * w3c[tj];
      }
#pragma unroll
      for (int m = 1; m <= 8; m <<= 1) pv += __shfl_xor(pv, m);
      rowpv[ti][r] = pv;
    }
  // B1s fully retired (last use was chunk-3 gemm1, sealed by its barrier).
  if (l15 == 0) {
#pragma unroll
    for (int ti = 0; ti < 4; ++ti)
#pragma unroll
      for (int r = 0; r < 4; ++r)
        outW[w * 64 + ti * 16 + quad * 4 + r] = rowpv[ti][r];
  }
  __syncthreads();
  if (tid < 64) {
    float z = b3[0];
#pragma unroll
    for (int k = 0; k < 8; ++k) z += outW[k * 64 + tid];
    out[mTile + tid] = 1.0f / (1.0f + expf(-z));
  }
}

extern "C" void kernel_launch(void* const* d_in, const int* in_sizes, int n_in,
                              void* d_out, int out_size, void* d_ws, size_t ws_size,
                              hipStream_t stream) {
  const float* x = (const float*)d_in[0];
  const float* W1 = (const float*)d_in[1];
  const float* b1 = (const float*)d_in[2];
  const float* g1 = (const float*)d_in[3];
  const float* be1 = (const float*)d_in[4];
  const float* m1 = (const float*)d_in[5];
  const float* v1 = (const float*)d_in[6];
  const float* W2 = (const float*)d_in[7];
  const float* b2 = (const float*)d_in[8];
  const float* g2 = (const float*)d_in[9];
  const float* be2 = (const float*)d_in[10];
  const float* m2 = (const float*)d_in[11];
  const float* v2 = (const float*)d_in[12];
  const float* W3 = (const float*)d_in[13];
  const float* b3 = (const float*)d_in[14];
  float* out = (float*)d_out;

  char* p = (char*)d_ws;
  bf16_t* h1 = (bf16_t*)p;       p += (size_t)65536 * 1024 * 2;  // unused (layout kept)
  float* partials = (float*)p;   p += (size_t)4 * 65536 * 4;     // unused
  bf16_t* W1T = (bf16_t*)p;      p += (size_t)1024 * 256 * 2;
  bf16_t* W2T = (bf16_t*)p;      p += (size_t)512 * 1024 * 2;
  float* w1last = (float*)p;     p += 1024 * 4;
  float* s1 = (float*)p;         p += 1024 * 4;
  float* t1 = (float*)p;         p += 1024 * 4;
  float* s2 = (float*)p;         p += 512 * 4;
  float* t2 = (float*)p;         p += 512 * 4;
  (void)h1;
  (void)partials;

  prep_weights_kernel<<<193, 256, 0, stream>>>(W1, W2, b1, g1, be1, m1, v1,
                                               b2, g2, be2, m2, v2,
                                               W1T, W2T, s1, t1, s2, t2, w1last);

  fused_mlp<<<1024, 512, 0, stream>>>(x, W1T, W2T, s1, t1, w1last,
                                      s2, t2, W3, b3, out);
}

// Round 8
// 300.356 us; speedup vs baseline: 1.2105x; 1.2105x over previous
//
#include <hip/hip_runtime.h>
#include <hip/hip_bf16.h>
#include <cstdint>
#include <cstddef>

typedef __bf16 bf16_t;
typedef bf16_t bf16x8 __attribute__((ext_vector_type(8)));
typedef float f32x4 __attribute__((ext_vector_type(4)));

#define BN_EPS 1e-5f

// r7: global_load_lds dest is wave-uniform base + lane*16B; source per-lane
// contiguous within lines; swizzle via pre-swizzled SOURCE only.
// r11: never duplicate reg-direct global reads across waves.
// r14 (174us): per-block fusion + 12 waves/CU. r15 (220us): h1 LDS-only kills
// 210MB traffic but 8 waves/CU is latency-bound.
// r17 (CLIFF): launch_bounds(512,4) -> 128 UNIFIED (VGPR+AGPR!) regs; needed
// ~135 -> allocator cliffed to 64 arch VGPR + 420MB scratch spill traffic.
// Pool is 512/wave-slot budget per SIMD; AGPR counts against it (gfx950
// unified file). r14 fit 148<=170 (256,3); r15 fit 256<=256 (256,2).
// r18: 1024-thread block on M=64 -> per-lane gemm2 acc = 64*512/1024 = 32 f32.
// Peak unified ~90 <= 128 -> 16 waves/CU WITHOUT spill. h1 LDS-only kept.
// Wave owns 32 N-cols (disjoint W2T reads); gemm1 16 cols/chunk/wave with
// depth-4 counted-vmcnt(3) wave-private staging. LDS 128KB, 1 block/CU.
__device__ __forceinline__ void async_load16(const bf16_t* g, bf16_t* lds) {
  __builtin_amdgcn_global_load_lds(
      (__attribute__((address_space(1))) uint32_t*)(g),
      (__attribute__((address_space(3))) uint32_t*)(lds),
      16, 0, 0);
}

// ---- Weight prep (transposes + BN folds), tiny ------------------------------
__global__ void prep_weights_kernel(const float* __restrict__ W1, const float* __restrict__ W2,
                                    const float* b1, const float* g1, const float* be1,
                                    const float* m1, const float* v1,
                                    const float* b2, const float* g2, const float* be2,
                                    const float* m2, const float* v2,
                                    bf16_t* __restrict__ W1T, bf16_t* __restrict__ W2T,
                                    float* s1, float* t1, float* s2, float* t2,
                                    float* w1last) {
  const int b = blockIdx.x;
  if (b < 192) {
    const float* src;
    bf16_t* dst;
    int R, C, bx, by;
    if (b < 64) { src = W1; dst = W1T; R = 256; C = 1024; bx = b & 15; by = b >> 4; }
    else        { src = W2; dst = W2T; R = 1024; C = 512; bx = (b - 64) & 7; by = (b - 64) >> 3; }
    __shared__ bf16_t tile[64][66];
    const int r0 = by * 64, c0 = bx * 64;
    const int tc = threadIdx.x & 63;
    const int tr4 = threadIdx.x >> 6;
#pragma unroll
    for (int i = 0; i < 16; ++i) {
      int r = i * 4 + tr4;
      tile[r][tc] = (bf16_t)src[(size_t)(r0 + r) * C + c0 + tc];  // coalesced read
    }
    __syncthreads();
#pragma unroll
    for (int i = 0; i < 16; ++i) {
      int rr = i * 4 + tr4;
      dst[(size_t)(c0 + rr) * R + r0 + tc] = tile[tc][rr];  // coalesced write
    }
  } else {
    for (int i = threadIdx.x; i < 1024; i += 256) {
      float s = g1[i] * rsqrtf(v1[i] + BN_EPS);
      s1[i] = s;
      t1[i] = be1[i] - m1[i] * s + b1[i] * s;  // bn(z+b1) = z*s + t
      w1last[i] = W1[256 * 1024 + i];          // conv-feature row (coalesced)
      if (i < 512) {
        float s2v = g2[i] * rsqrtf(v2[i] + BN_EPS);
        s2[i] = s2v;
        t2[i] = be2[i] - m2[i] * s2v + b2[i] * s2v;
      }
    }
  }
}

// ---- Fully-fused per-block MLP: 64 rows, 16 waves, h1 LDS-only --------------
// LDS 128 KB: As[64][256] 32K (chunk-swizzled) | h1c[64][256] 32K
// (chunk-swizzled; convs[64] overlays pre-use) | B1s 16 waves x 4 stages x 1K
// = 64K (outW[16][64] overlays at the end).
__global__ __launch_bounds__(1024, 4) void fused_mlp(
    const float* __restrict__ x,
    const bf16_t* __restrict__ W1T, const bf16_t* __restrict__ W2T,
    const float* __restrict__ s1, const float* __restrict__ t1,
    const float* __restrict__ w1last,
    const float* __restrict__ s2, const float* __restrict__ t2,
    const float* __restrict__ W3, const float* __restrict__ b3,
    float* __restrict__ out) {
  __shared__ __align__(16) unsigned char smem[131072];
  const int tid = threadIdx.x;
  const int lane = tid & 63;
  const int w = tid >> 6;          // 0..15
  const int l15 = lane & 15;
  const int quad = lane >> 4;
  const int mTile = blockIdx.x * 64;

  bf16_t* As = (bf16_t*)smem;                 // [64][256], chunk-swizzled
  bf16_t* h1c = (bf16_t*)(smem + 32768);      // [64][256], chunk-swizzled
  float* convs = (float*)(smem + 32768);      // overlay (pre-h1c use)
  bf16_t* B1s = (bf16_t*)(smem + 65536);      // [16 waves][4 bufs][512 elems]
  float* outW = (float*)(smem + 65536);       // overlay (post-B1s use)

  // ---- prologue: x fp32 -> bf16 into As (swizzled), per-row conv ----------
  {
    const int rsub = lane >> 5;     // 0..1
    const int cc = lane & 31;       // 8-elem chunk within row
#pragma unroll
    for (int i = 0; i < 2; ++i) {
      int row = w * 4 + i * 2 + rsub;
      const float* gx = x + (size_t)(mTile + row) * 256 + cc * 8;
      const float4 a = *(const float4*)gx;
      const float4 bq = *(const float4*)(gx + 4);
      float s = a.x + a.y + a.z + a.w + bq.x + bq.y + bq.z + bq.w;
      bf16x8 v = {(bf16_t)a.x, (bf16_t)a.y, (bf16_t)a.z, (bf16_t)a.w,
                  (bf16_t)bq.x, (bf16_t)bq.y, (bf16_t)bq.z, (bf16_t)bq.w};
      *(bf16x8*)(As + row * 256 + (cc ^ (row & 7)) * 8) = v;
#pragma unroll
      for (int m = 1; m <= 16; m <<= 1) s += __shfl_xor(s, m);  // 32-lane groups
      if (cc == 0) convs[row] = (s > 0.0f) ? 1.0f : 0.0f;  // mean>0 <=> sum>0
    }
  }
  __syncthreads();  // As + convs visible

  // Conv feature bitmask over the 16 output rows this lane owns (4 row-tiles).
  unsigned cmask = 0;
#pragma unroll
  for (int ti = 0; ti < 4; ++ti)
#pragma unroll
    for (int r = 0; r < 4; ++r)
      if (convs[ti * 16 + quad * 4 + r] > 0.5f) cmask |= (1u << (ti * 4 + r));
  // convs-read vs h1c-write WAR is sealed by chunk 0's pre-store barrier.

  bf16_t* B1w = B1s + w * 2048;         // wave-private: 4 bufs x 512 elems
  const int srow = lane >> 2;           // 0..15
  const int schunk = (lane & 3) ^ ((lane >> 3) & 3);   // pre-swizzled src chunk
  const int rchunk = quad ^ ((l15 >> 1) & 3);          // read-side inverse

  // Persistent gemm2 accumulators: wave owns N-cols [w*32, w*32+32).
  f32x4 acc2[4][2];
#pragma unroll
  for (int i = 0; i < 4; ++i)
#pragma unroll
    for (int j = 0; j < 2; ++j) {
      f32x4 z = {0.f, 0.f, 0.f, 0.f};
      acc2[i][j] = z;
    }

  for (int c = 0; c < 4; ++c) {
    // ---- gemm1: wave w owns cols c*256 + w*16 .. +15 (one 16-col pass) ----
    const int colbase = c * 256 + w * 16;
    f32x4 acc1[4];
#pragma unroll
    for (int i = 0; i < 4; ++i) {
      f32x4 z = {0.f, 0.f, 0.f, 0.f};
      acc1[i] = z;
    }

    const bf16_t* gB1 = W1T + (size_t)(colbase + srow) * 256 + schunk * 8;

    // Depth-4 prologue: stages ks=0..3 (1 KB each), 4 in flight.
#pragma unroll
    for (int p = 0; p < 4; ++p)
      async_load16(gB1 + p * 32, B1w + p * 512 + lane * 8);

#pragma unroll
    for (int ks = 0; ks < 8; ++ks) {
      if (ks < 5)      asm volatile("s_waitcnt vmcnt(3)" ::: "memory");
      else if (ks == 5) asm volatile("s_waitcnt vmcnt(2)" ::: "memory");
      else if (ks == 6) asm volatile("s_waitcnt vmcnt(1)" ::: "memory");
      else              asm volatile("s_waitcnt vmcnt(0)" ::: "memory");
      __builtin_amdgcn_sched_barrier(0);  // rule #18: pin reads below wait

      bf16x8 bfr = *(const bf16x8*)(B1w + (ks & 3) * 512 + l15 * 32 + rchunk * 8);
      bf16x8 af[4];
#pragma unroll
      for (int ti = 0; ti < 4; ++ti)
        af[ti] = *(const bf16x8*)(As + (ti * 16 + l15) * 256 +
                                  ((ks * 4 + quad) ^ (l15 & 7)) * 8);

      asm volatile("s_waitcnt lgkmcnt(0)" ::: "memory");  // frags in regs
      __builtin_amdgcn_sched_barrier(0);  // rule #18: MFMA must not hoist
      if (ks < 4)
        async_load16(gB1 + (ks + 4) * 32, B1w + (ks & 3) * 512 + lane * 8);

      __builtin_amdgcn_s_setprio(1);
#pragma unroll
      for (int ti = 0; ti < 4; ++ti)
        acc1[ti] = __builtin_amdgcn_mfma_f32_16x16x32_bf16(af[ti], bfr, acc1[ti], 0, 0, 0);
      __builtin_amdgcn_s_setprio(0);
    }

    __syncthreads();  // WAR: all waves done reading h1c (chunk c-1) / convs (c=0)

    // Epilogue: conv rank-1 + BN1 + ReLU -> h1c (LDS, swizzled)
    {
      const int ccol = colbase + l15;
      const float sc1 = s1[ccol];
      const float tc1 = t1[ccol];
      const float wl1 = w1last[ccol];
      const int colc = w * 16 + l15;   // 0..255 within chunk
#pragma unroll
      for (int ti = 0; ti < 4; ++ti)
#pragma unroll
        for (int r = 0; r < 4; ++r) {
          const int rowl = ti * 16 + quad * 4 + r;
          const float cfv = ((cmask >> (ti * 4 + r)) & 1u) ? 1.0f : 0.0f;
          float z = acc1[ti][r] + cfv * wl1;
          z = fmaxf(z * sc1 + tc1, 0.f);
          const int c8 = (colc >> 3) ^ (rowl & 7);
          h1c[rowl * 256 + c8 * 8 + (l15 & 7)] = (bf16_t)z;
        }
    }
    __syncthreads();  // h1c chunk complete + visible

    // ---- gemm2 partial: K-range [c*256,(c+1)*256), N = wave's 32 cols.
    // B reg-direct from L2 (disjoint per wave); A from h1c LDS. No barriers.
#pragma unroll
    for (int s = 0; s < 8; ++s) {
      bf16x8 bfr2[2];
#pragma unroll
      for (int tj = 0; tj < 2; ++tj)
        bfr2[tj] = *(const bf16x8*)(W2T + (size_t)(w * 32 + tj * 16 + l15) * 1024 +
                                    c * 256 + s * 32 + quad * 8);
#pragma unroll
      for (int ti = 0; ti < 4; ++ti) {
        bf16x8 af2 = *(const bf16x8*)(h1c + (ti * 16 + l15) * 256 +
                                      ((s * 4 + quad) ^ (l15 & 7)) * 8);
        __builtin_amdgcn_s_setprio(1);
        acc2[ti][0] = __builtin_amdgcn_mfma_f32_16x16x32_bf16(af2, bfr2[0], acc2[ti][0], 0, 0, 0);
        acc2[ti][1] = __builtin_amdgcn_mfma_f32_16x16x32_bf16(af2, bfr2[1], acc2[ti][1], 0, 0, 0);
        __builtin_amdgcn_s_setprio(0);
      }
    }
  }

  // ---- final epilogue: BN2 + ReLU + dot W3 over this wave's 32 N-cols ----
  float sc[2], tcs[2], w3c[2];
#pragma unroll
  for (int tj = 0; tj < 2; ++tj) {
    int ccol = w * 32 + tj * 16 + l15;
    sc[tj] = s2[ccol];
    tcs[tj] = t2[ccol];
    w3c[tj] = W3[ccol];
  }
  // B1s fully retired: every wave's last staging drained by its ks=7 vmcnt(0),
  // and all waves passed chunk-3's h1c barrier before reaching here.
#pragma unroll
  for (int ti = 0; ti < 4; ++ti)
#pragma unroll
    for (int r = 0; r < 4; ++r) {
      float pv = 0.f;
#pragma unroll
      for (int tj = 0; tj < 2; ++tj) {
        float z = fmaxf(acc2[ti][tj][r] * sc[tj] + tcs[tj], 0.f);
        pv += z * w3c[tj];
      }
#pragma unroll
      for (int m = 1; m <= 8; m <<= 1) pv += __shfl_xor(pv, m);
      if (l15 == 0)
        outW[w * 64 + ti * 16 + quad * 4 + r] = pv;
    }
  __syncthreads();
  if (tid < 64) {
    float z = b3[0];
#pragma unroll
    for (int k = 0; k < 16; ++k) z += outW[k * 64 + tid];
    out[mTile + tid] = 1.0f / (1.0f + expf(-z));
  }
}

extern "C" void kernel_launch(void* const* d_in, const int* in_sizes, int n_in,
                              void* d_out, int out_size, void* d_ws, size_t ws_size,
                              hipStream_t stream) {
  const float* x = (const float*)d_in[0];
  const float* W1 = (const float*)d_in[1];
  const float* b1 = (const float*)d_in[2];
  const float* g1 = (const float*)d_in[3];
  const float* be1 = (const float*)d_in[4];
  const float* m1 = (const float*)d_in[5];
  const float* v1 = (const float*)d_in[6];
  const float* W2 = (const float*)d_in[7];
  const float* b2 = (const float*)d_in[8];
  const float* g2 = (const float*)d_in[9];
  const float* be2 = (const float*)d_in[10];
  const float* m2 = (const float*)d_in[11];
  const float* v2 = (const float*)d_in[12];
  const float* W3 = (const float*)d_in[13];
  const float* b3 = (const float*)d_in[14];
  float* out = (float*)d_out;

  char* p = (char*)d_ws;
  bf16_t* h1 = (bf16_t*)p;       p += (size_t)65536 * 1024 * 2;  // unused (layout kept)
  float* partials = (float*)p;   p += (size_t)4 * 65536 * 4;     // unused
  bf16_t* W1T = (bf16_t*)p;      p += (size_t)1024 * 256 * 2;
  bf16_t* W2T = (bf16_t*)p;      p += (size_t)512 * 1024 * 2;
  float* w1last = (float*)p;     p += 1024 * 4;
  float* s1 = (float*)p;         p += 1024 * 4;
  float* t1 = (float*)p;         p += 1024 * 4;
  float* s2 = (float*)p;         p += 512 * 4;
  float* t2 = (float*)p;         p += 512 * 4;
  (void)h1;
  (void)partials;

  prep_weights_kernel<<<193, 256, 0, stream>>>(W1, W2, b1, g1, be1, m1, v1,
                                               b2, g2, be2, m2, v2,
                                               W1T, W2T, s1, t1, s2, t2, w1last);

  fused_mlp<<<1024, 1024, 0, stream>>>(x, W1T, W2T, s1, t1, w1last,
                                       s2, t2, W3, b3, out);
}